// Round 10
// baseline (44.725 us; speedup 1.0000x reference)
//
#include <hip/hip_runtime.h>

#define IMG_H 512
#define IMG_W 512
#define HW    (IMG_H * IMG_W)
#define NCH   24   // 8 batches * 3 channels

__device__ __forceinline__ float fexp2(float x) {
#if __has_builtin(__builtin_amdgcn_exp2f)
    return __builtin_amdgcn_exp2f(x);
#else
    float r; asm("v_exp_f32 %0, %1" : "=v"(r) : "v"(x)); return r;
#endif
}
__device__ __forceinline__ float frcp(float x) {
#if __has_builtin(__builtin_amdgcn_rcpf)
    return __builtin_amdgcn_rcpf(x);
#else
    float r; asm("v_rcp_f32 %0, %1" : "=v"(r) : "v"(x)); return r;
#endif
}

// exp(-r2/2) (double, folded at compile time)
__device__ __forceinline__ constexpr double exs(int r2) {
    return (r2 == 0) ? 1.0
         : (r2 == 1) ? 0.60653065971263342
         : (r2 == 2) ? 0.36787944117144233
         : (r2 == 4) ? 0.13533528323661270
         : (r2 == 5) ? 0.08208499862389880
         : (r2 == 8) ? 0.01831563888873418 : 0.0;
}
#define SSUM 6.16892408102888092
__device__ __forceinline__ constexpr float k1(int d)  { return (float)exs(d * d); }
__device__ __forceinline__ constexpr float k1n(int d) { return (float)(exs(d * d) / SSUM); }
// -50/ln2 (intensity) and -0.5/ln2 (spatial, per unit r2), log2 domain
#define NEG50  -72.134752044448169f
#define LG     -0.72134752044448169f

// Border first: 4 full rows (y=0,1,510,511)*128 groups + 508 rows * 2 edge groups
#define PER_CH_B (4 * 128 + 508 * 2)      // 1528
#define N_B (PER_CH_B * NCH)              // 36,672
// Main: threads own TWO stacked 4x4 tiles (8 rows x 4 cols). x0 in {4..504} (126),
// y0 in {2,10,...,498} (63) covering rows 2..505
#define XT 126
#define KY 63
#define PER_CH_M (XT * KY)                // 7938
#define N_MAIN (PER_CH_M * NCH)           // 190,512
// Remainder band: rows 506..509, one 4x4 tile per thread
#define PER_CH_R XT                       // 126
#define N_REM (PER_CH_R * NCH)            // 3,024
#define N_TOTAL (N_B + N_MAIN + N_REM)    // 230,208

__global__ __launch_bounds__(256) void aa_kernel(const float* __restrict__ in,
                                                 float* __restrict__ out) {
    const int gid = blockIdx.x * 256 + threadIdx.x;

    if (gid < N_B) {
        // ---------- border (dispatched FIRST; latency hides under interior) ----------
        const int ch = gid / PER_CH_B;
        const int r  = gid - ch * PER_CH_B;
        int y, x0;
        if (r < 512) {
            const int q = r >> 7;                 // 0..3 -> rows {0,1,510,511}
            y  = (q < 2) ? q : q + 508;
            x0 = (r & 127) << 2;
        } else {
            const int t = r - 512;
            y  = 2 + (t >> 1);
            x0 = (t & 1) ? (IMG_W - 4) : 0;
        }
        const float* __restrict__ img = in + ch * HW;

        int ry[5]; float krow[5];
        #pragma unroll
        for (int i = 0; i < 5; ++i) {
            const int yy = y + i - 2;
            const int ryy = (yy < 0) ? -yy : ((yy >= IMG_H) ? 2 * IMG_H - 2 - yy : yy);
            ry[i] = ryy * IMG_W;
            krow[i] = ((yy >= 0) & (yy < IMG_H)) ? k1(i - 2) : 0.0f;
        }
        int rx[8]; float xin[8];
        #pragma unroll
        for (int c = 0; c < 8; ++c) {
            const int xx = x0 + c - 2;
            rx[c] = (xx < 0) ? -xx : ((xx >= IMG_W) ? 2 * IMG_W - 2 - xx : xx);
            xin[c] = ((xx >= 0) & (xx < IMG_W)) ? 1.0f : 0.0f;
        }
        float v[5][8];
        #pragma unroll
        for (int i = 0; i < 5; ++i) {
            #pragma unroll
            for (int c = 0; c < 8; ++c) v[i][c] = img[ry[i] + rx[c]];
        }

        float csm[8];
        #pragma unroll
        for (int c = 0; c < 8; ++c) {
            float s = krow[0] * v[0][c];
            s = fmaf(krow[1], v[1][c], s);
            s = fmaf(krow[2], v[2][c], s);
            s = fmaf(krow[3], v[3][c], s);
            s = fmaf(krow[4], v[4][c], s);
            csm[c] = s * xin[c];
        }

        float res[4];
        #pragma unroll
        for (int p = 0; p < 4; ++p) {
            const float ctr = v[2][2 + p];
            float arg[24];
            {
                int t = 0;
                #pragma unroll
                for (int i = 0; i < 5; ++i) {
                    #pragma unroll
                    for (int j = 0; j < 5; ++j) {
                        if (i == 2 && j == 2) continue;   // center: w == 1
                        const int r2 = (i - 2) * (i - 2) + (j - 2) * (j - 2);
                        const float d = v[i][p + j] - ctr;
                        arg[t] = fmaf(d * d, NEG50, LG * (float)r2);
                        ++t;
                    }
                }
            }
            float w[24];
            #pragma unroll
            for (int k = 0; k < 24; ++k) w[k] = fexp2(arg[k]);

            float ws0 = 1.0f, ws1 = 0.f, ws2 = 0.f, ws3 = 0.f;
            float bs0 = ctr,  bs1 = 0.f, bs2 = 0.f, bs3 = 0.f;
            {
                int t = 0;
                #pragma unroll
                for (int i = 0; i < 5; ++i) {
                    #pragma unroll
                    for (int j = 0; j < 5; ++j) {
                        if (i == 2 && j == 2) continue;
                        const float vv = v[i][p + j];
                        if ((t & 3) == 0)      { ws0 += w[t]; bs0 = fmaf(w[t], vv, bs0); }
                        else if ((t & 3) == 1) { ws1 += w[t]; bs1 = fmaf(w[t], vv, bs1); }
                        else if ((t & 3) == 2) { ws2 += w[t]; bs2 = fmaf(w[t], vv, bs2); }
                        else                   { ws3 += w[t]; bs3 = fmaf(w[t], vv, bs3); }
                        ++t;
                    }
                }
            }
            const float wsum = (ws0 + ws1) + (ws2 + ws3);
            const float bsum = (bs0 + bs1) + (bs2 + bs3);

            float g = k1n(2) * csm[p];
            g = fmaf(k1n(1), csm[p + 1], g);
            g = fmaf(k1n(0), csm[p + 2], g);
            g = fmaf(k1n(1), csm[p + 3], g);
            g = fmaf(k1n(2), csm[p + 4], g);

            res[p] = fmaf(0.6f, g, 0.4f * (bsum * frcp(wsum + 1e-8f)));
        }

        float4* o4 = (float4*)(out + ch * HW + y * IMG_W + x0);
        *o4 = make_float4(res[0], res[1], res[2], res[3]);
    } else {
        // -------- interior: 1-2 stacked 4x4 tiles, symmetric weight sharing --------
        const int ig = gid - N_B;
        int ch, x0, y0, ntiles;
        if (ig < N_MAIN) {
            ch = ig / PER_CH_M;
            const int rem = ig - ch * PER_CH_M;
            const int ky = rem / XT;
            y0 = 2 + 8 * ky;
            x0 = 4 + (rem - ky * XT) * 4;
            ntiles = 2;
        } else {
            const int ir = ig - N_MAIN;
            if (ir >= N_REM) return;              // grid pad guard
            ch = ir / PER_CH_R;
            x0 = 4 + (ir - ch * PER_CH_R) * 4;
            y0 = 506;
            ntiles = 1;
        }

        const float* __restrict__ img = in + ch * HW;
        const float* base = img + (y0 - 2) * IMG_W + (x0 - 2);

        // 8x8 window: base rows 0..7 (= image rows y0-2 .. y0+5), cols x0-2..x0+5
        float v[8][8];
        #pragma unroll
        for (int r = 0; r < 8; ++r) {
            const float2* rp = (const float2*)(base + r * IMG_W);
            #pragma unroll
            for (int c = 0; c < 4; ++c) {
                const float2 t = rp[c];
                v[r][2 * c]     = t.x;
                v[r][2 * c + 1] = t.y;
            }
        }

        float* op = out + ch * HW + y0 * IMG_W + x0;

        #pragma unroll 1                           // keep ONE copy of the body (I$)
        for (int t = 0; t < ntiles; ++t) {
            if (t) {
                // shift window down 4 rows; load base rows 8..11 (image y0+6..y0+9)
                #pragma unroll
                for (int r = 0; r < 4; ++r) {
                    #pragma unroll
                    for (int c = 0; c < 8; ++c) v[r][c] = v[r + 4][c];
                }
                #pragma unroll
                for (int r = 4; r < 8; ++r) {
                    const float2* rp = (const float2*)(base + (r + 4) * IMG_W);
                    #pragma unroll
                    for (int c = 0; c < 4; ++c) {
                        const float2 tt = rp[c];
                        v[r][2 * c]     = tt.x;
                        v[r][2 * c + 1] = tt.y;
                    }
                }
            }

            // accumulators: center tap folded in (w == 1)
            float ws[16], bs[16];
            #pragma unroll
            for (int p = 0; p < 16; ++p) {
                const int pr = p >> 2, pc = p & 3;
                ws[p] = 1.0f;
                bs[p] = v[pr + 2][pc + 2];
            }

            // 12 lexicographically-positive offsets (di,dj)
            constexpr int PDI[12] = {0, 0, 1,  1, 1, 1, 1, 2,  2, 2, 2, 2};
            constexpr int PDJ[12] = {1, 2, -2, -1, 0, 1, 2, -2, -1, 0, 1, 2};

            // positive pass: each shared weight once; scatter to both endpoints
            #pragma unroll
            for (int o = 0; o < 12; ++o) {
                const int di = PDI[o], dj = PDJ[o];
                const int r2 = di * di + dj * dj;
                const float lsw = LG * (float)r2;
                float wt[16];
                #pragma unroll
                for (int p = 0; p < 16; ++p) {
                    const int pr = p >> 2, pc = p & 3;
                    const float d = v[pr + 2 + di][pc + 2 + dj] - v[pr + 2][pc + 2];
                    wt[p] = fexp2(fmaf(d * d, NEG50, lsw));
                }
                #pragma unroll
                for (int p = 0; p < 16; ++p) {
                    const int pr = p >> 2, pc = p & 3;
                    const float vp = v[pr + 2][pc + 2];
                    const float vt = v[pr + 2 + di][pc + 2 + dj];
                    ws[p] += wt[p];
                    bs[p] = fmaf(wt[p], vt, bs[p]);
                    const int qr = pr + di, qc = pc + dj;
                    if (qr >= 0 && qr < 4 && qc >= 0 && qc < 4) {   // compile-time
                        const int q = qr * 4 + qc;
                        ws[q] += wt[p];
                        bs[q] = fmaf(wt[p], vp, bs[q]);
                    }
                }
            }
            // negative pass: only instances whose mirror endpoint is outside the tile
            #pragma unroll
            for (int o = 0; o < 12; ++o) {
                const int di = -PDI[o], dj = -PDJ[o];
                const int r2 = di * di + dj * dj;
                const float lsw = LG * (float)r2;
                float wt[16];
                #pragma unroll
                for (int p = 0; p < 16; ++p) {
                    const int pr = p >> 2, pc = p & 3;
                    const int qr = pr + di, qc = pc + dj;
                    if (qr < 0 || qr >= 4 || qc < 0 || qc >= 4) {   // compile-time
                        const float d = v[pr + 2 + di][pc + 2 + dj] - v[pr + 2][pc + 2];
                        wt[p] = fexp2(fmaf(d * d, NEG50, lsw));
                    }
                }
                #pragma unroll
                for (int p = 0; p < 16; ++p) {
                    const int pr = p >> 2, pc = p & 3;
                    const int qr = pr + di, qc = pc + dj;
                    if (qr < 0 || qr >= 4 || qc < 0 || qc >= 4) {
                        const float vt = v[pr + 2 + di][pc + 2 + dj];
                        ws[p] += wt[p];
                        bs[p] = fmaf(wt[p], vt, bs[p]);
                    }
                }
            }

            // separable gaussian: column pass (unnormalized), row pass (normalized)
            float cs[4][8];
            #pragma unroll
            for (int yr = 0; yr < 4; ++yr) {
                #pragma unroll
                for (int c = 0; c < 8; ++c) {
                    float s = k1(2) * v[yr][c];
                    s = fmaf(k1(1), v[yr + 1][c], s);
                    s = fmaf(k1(0), v[yr + 2][c], s);
                    s = fmaf(k1(1), v[yr + 3][c], s);
                    s = fmaf(k1(2), v[yr + 4][c], s);
                    cs[yr][c] = s;
                }
            }

            float* opt = op + t * 4 * IMG_W;
            #pragma unroll
            for (int yr = 0; yr < 4; ++yr) {
                float res[4];
                #pragma unroll
                for (int pc = 0; pc < 4; ++pc) {
                    float g = k1n(2) * cs[yr][pc];
                    g = fmaf(k1n(1), cs[yr][pc + 1], g);
                    g = fmaf(k1n(0), cs[yr][pc + 2], g);
                    g = fmaf(k1n(1), cs[yr][pc + 3], g);
                    const int p = yr * 4 + pc;
                    g = fmaf(k1n(2), cs[yr][pc + 4], g);
                    res[pc] = fmaf(0.6f, g, 0.4f * (bs[p] * frcp(ws[p] + 1e-8f)));
                }
                *(float4*)(opt + yr * IMG_W) = make_float4(res[0], res[1], res[2], res[3]);
            }
        }
    }
}

extern "C" void kernel_launch(void* const* d_in, const int* in_sizes, int n_in,
                              void* d_out, int out_size, void* d_ws, size_t ws_size,
                              hipStream_t stream) {
    const float* img = (const float*)d_in[0];
    float* out = (float*)d_out;
    const int blocks = (N_TOTAL + 255) / 256;     // 900
    aa_kernel<<<blocks, 256, 0, stream>>>(img, out);
}

// Round 11
// 40.213 us; speedup vs baseline: 1.1122x; 1.1122x over previous
//
#include <hip/hip_runtime.h>

#define IMG_H 512
#define IMG_W 512
#define HW    (IMG_H * IMG_W)
#define NCH   24   // 8 batches * 3 channels

__device__ __forceinline__ float fexp2(float x) {
#if __has_builtin(__builtin_amdgcn_exp2f)
    return __builtin_amdgcn_exp2f(x);
#else
    float r; asm("v_exp_f32 %0, %1" : "=v"(r) : "v"(x)); return r;
#endif
}
__device__ __forceinline__ float frcp(float x) {
#if __has_builtin(__builtin_amdgcn_rcpf)
    return __builtin_amdgcn_rcpf(x);
#else
    float r; asm("v_rcp_f32 %0, %1" : "=v"(r) : "v"(x)); return r;
#endif
}

// exp(-r2/2) (double, folded at compile time)
__device__ __forceinline__ constexpr double exs(int r2) {
    return (r2 == 0) ? 1.0
         : (r2 == 1) ? 0.60653065971263342
         : (r2 == 2) ? 0.36787944117144233
         : (r2 == 4) ? 0.13533528323661270
         : (r2 == 5) ? 0.08208499862389880
         : (r2 == 8) ? 0.01831563888873418 : 0.0;
}
#define SSUM 6.16892408102888092
__device__ __forceinline__ constexpr float k1(int d)  { return (float)exs(d * d); }
__device__ __forceinline__ constexpr float k1n(int d) { return (float)(exs(d * d) / SSUM); }
// -50/ln2 (intensity) and -0.5/ln2 (spatial, per unit r2), log2 domain
#define NEG50  -72.134752044448169f
#define LG     -0.72134752044448169f

// Work-item space: border groups first (wave-aligned), then 4x4 interior tiles.
#define PER_CH_B (4 * 128 + 508 * 2)      // 1528
#define N_B (PER_CH_B * NCH)              // 36,672 = 573 waves exactly
#define XT 126
#define YT 127
#define PER_CH_T (XT * YT)                // 16002 tiles/channel
#define N_INT (PER_CH_T * NCH)            // 384,048 tiles
#define N_TOTAL (N_B + N_INT)             // 420,720 work items

// Persistent grid: 768 blocks (3 blocks/CU on 256 CUs), grid-stride over items.
#define GRID_BLOCKS 768
#define STRIDE (GRID_BLOCKS * 256)        // 196,608 threads -> ~2.14 items/thread

__global__ __launch_bounds__(256) void aa_kernel(const float* __restrict__ in,
                                                 float* __restrict__ out) {
    const int tid0 = blockIdx.x * 256 + threadIdx.x;

    for (int gid = tid0; gid < N_TOTAL; gid += STRIDE) {
        if (gid < N_B) {
            // ---------- border (first 573 waves of item space) ----------
            const int ch = gid / PER_CH_B;
            const int r  = gid - ch * PER_CH_B;
            int y, x0;
            if (r < 512) {
                const int q = r >> 7;             // 0..3 -> rows {0,1,510,511}
                y  = (q < 2) ? q : q + 508;
                x0 = (r & 127) << 2;
            } else {
                const int t = r - 512;
                y  = 2 + (t >> 1);
                x0 = (t & 1) ? (IMG_W - 4) : 0;
            }
            const float* __restrict__ img = in + ch * HW;

            int ry[5]; float krow[5];
            #pragma unroll
            for (int i = 0; i < 5; ++i) {
                const int yy = y + i - 2;
                const int ryy = (yy < 0) ? -yy : ((yy >= IMG_H) ? 2 * IMG_H - 2 - yy : yy);
                ry[i] = ryy * IMG_W;
                krow[i] = ((yy >= 0) & (yy < IMG_H)) ? k1(i - 2) : 0.0f;
            }
            int rx[8]; float xin[8];
            #pragma unroll
            for (int c = 0; c < 8; ++c) {
                const int xx = x0 + c - 2;
                rx[c] = (xx < 0) ? -xx : ((xx >= IMG_W) ? 2 * IMG_W - 2 - xx : xx);
                xin[c] = ((xx >= 0) & (xx < IMG_W)) ? 1.0f : 0.0f;
            }
            float v[5][8];
            #pragma unroll
            for (int i = 0; i < 5; ++i) {
                #pragma unroll
                for (int c = 0; c < 8; ++c) v[i][c] = img[ry[i] + rx[c]];
            }

            float csm[8];
            #pragma unroll
            for (int c = 0; c < 8; ++c) {
                float s = krow[0] * v[0][c];
                s = fmaf(krow[1], v[1][c], s);
                s = fmaf(krow[2], v[2][c], s);
                s = fmaf(krow[3], v[3][c], s);
                s = fmaf(krow[4], v[4][c], s);
                csm[c] = s * xin[c];
            }

            float res[4];
            #pragma unroll
            for (int p = 0; p < 4; ++p) {
                const float ctr = v[2][2 + p];
                float arg[24];
                {
                    int t = 0;
                    #pragma unroll
                    for (int i = 0; i < 5; ++i) {
                        #pragma unroll
                        for (int j = 0; j < 5; ++j) {
                            if (i == 2 && j == 2) continue;   // center: w == 1
                            const int r2 = (i - 2) * (i - 2) + (j - 2) * (j - 2);
                            const float d = v[i][p + j] - ctr;
                            arg[t] = fmaf(d * d, NEG50, LG * (float)r2);
                            ++t;
                        }
                    }
                }
                float w[24];
                #pragma unroll
                for (int k = 0; k < 24; ++k) w[k] = fexp2(arg[k]);

                float ws0 = 1.0f, ws1 = 0.f, ws2 = 0.f, ws3 = 0.f;
                float bs0 = ctr,  bs1 = 0.f, bs2 = 0.f, bs3 = 0.f;
                {
                    int t = 0;
                    #pragma unroll
                    for (int i = 0; i < 5; ++i) {
                        #pragma unroll
                        for (int j = 0; j < 5; ++j) {
                            if (i == 2 && j == 2) continue;
                            const float vv = v[i][p + j];
                            if ((t & 3) == 0)      { ws0 += w[t]; bs0 = fmaf(w[t], vv, bs0); }
                            else if ((t & 3) == 1) { ws1 += w[t]; bs1 = fmaf(w[t], vv, bs1); }
                            else if ((t & 3) == 2) { ws2 += w[t]; bs2 = fmaf(w[t], vv, bs2); }
                            else                   { ws3 += w[t]; bs3 = fmaf(w[t], vv, bs3); }
                            ++t;
                        }
                    }
                }
                const float wsum = (ws0 + ws1) + (ws2 + ws3);
                const float bsum = (bs0 + bs1) + (bs2 + bs3);

                float g = k1n(2) * csm[p];
                g = fmaf(k1n(1), csm[p + 1], g);
                g = fmaf(k1n(0), csm[p + 2], g);
                g = fmaf(k1n(1), csm[p + 3], g);
                g = fmaf(k1n(2), csm[p + 4], g);

                res[p] = fmaf(0.6f, g, 0.4f * (bsum * frcp(wsum + 1e-8f)));
            }

            float4* o4 = (float4*)(out + ch * HW + y * IMG_W + x0);
            *o4 = make_float4(res[0], res[1], res[2], res[3]);
        } else {
            // -------- interior: 4x4 tile with symmetric bilateral-weight sharing --------
            const int ig = gid - N_B;
            const int ch  = ig / PER_CH_T;
            const int rem = ig - ch * PER_CH_T;
            const int ty  = rem / XT;
            const int y0  = 2 + ty * 4;           // top output row
            const int x0  = 4 + (rem - ty * XT) * 4;

            const float* __restrict__ img = in + ch * HW;
            const float* base = img + (y0 - 2) * IMG_W + (x0 - 2);

            // 8x8 window: rows y0-2..y0+5, cols x0-2..x0+5
            float v[8][8];
            #pragma unroll
            for (int r = 0; r < 8; ++r) {
                const float2* rp = (const float2*)(base + r * IMG_W);
                #pragma unroll
                for (int c = 0; c < 4; ++c) {
                    const float2 t = rp[c];
                    v[r][2 * c]     = t.x;
                    v[r][2 * c + 1] = t.y;
                }
            }

            float ws[16], bs[16];
            #pragma unroll
            for (int p = 0; p < 16; ++p) {
                const int pr = p >> 2, pc = p & 3;
                ws[p] = 1.0f;
                bs[p] = v[pr + 2][pc + 2];
            }

            constexpr int PDI[12] = {0, 0, 1,  1, 1, 1, 1, 2,  2, 2, 2, 2};
            constexpr int PDJ[12] = {1, 2, -2, -1, 0, 1, 2, -2, -1, 0, 1, 2};

            // positive pass: each shared weight once; scatter to both endpoints
            #pragma unroll
            for (int o = 0; o < 12; ++o) {
                const int di = PDI[o], dj = PDJ[o];
                const int r2 = di * di + dj * dj;
                const float lsw = LG * (float)r2;
                float wt[16];
                #pragma unroll
                for (int p = 0; p < 16; ++p) {
                    const int pr = p >> 2, pc = p & 3;
                    const float d = v[pr + 2 + di][pc + 2 + dj] - v[pr + 2][pc + 2];
                    wt[p] = fexp2(fmaf(d * d, NEG50, lsw));
                }
                #pragma unroll
                for (int p = 0; p < 16; ++p) {
                    const int pr = p >> 2, pc = p & 3;
                    const float vp = v[pr + 2][pc + 2];
                    const float vt = v[pr + 2 + di][pc + 2 + dj];
                    ws[p] += wt[p];
                    bs[p] = fmaf(wt[p], vt, bs[p]);
                    const int qr = pr + di, qc = pc + dj;
                    if (qr >= 0 && qr < 4 && qc >= 0 && qc < 4) {   // compile-time
                        const int q = qr * 4 + qc;
                        ws[q] += wt[p];
                        bs[q] = fmaf(wt[p], vp, bs[q]);
                    }
                }
            }
            // negative pass: only instances whose mirror endpoint is outside the tile
            #pragma unroll
            for (int o = 0; o < 12; ++o) {
                const int di = -PDI[o], dj = -PDJ[o];
                const int r2 = di * di + dj * dj;
                const float lsw = LG * (float)r2;
                float wt[16];
                #pragma unroll
                for (int p = 0; p < 16; ++p) {
                    const int pr = p >> 2, pc = p & 3;
                    const int qr = pr + di, qc = pc + dj;
                    if (qr < 0 || qr >= 4 || qc < 0 || qc >= 4) {   // compile-time
                        const float d = v[pr + 2 + di][pc + 2 + dj] - v[pr + 2][pc + 2];
                        wt[p] = fexp2(fmaf(d * d, NEG50, lsw));
                    }
                }
                #pragma unroll
                for (int p = 0; p < 16; ++p) {
                    const int pr = p >> 2, pc = p & 3;
                    const int qr = pr + di, qc = pc + dj;
                    if (qr < 0 || qr >= 4 || qc < 0 || qc >= 4) {
                        const float vt = v[pr + 2 + di][pc + 2 + dj];
                        ws[p] += wt[p];
                        bs[p] = fmaf(wt[p], vt, bs[p]);
                    }
                }
            }

            // separable gaussian: column pass (unnormalized), row pass (normalized)
            float cs[4][8];
            #pragma unroll
            for (int yr = 0; yr < 4; ++yr) {
                #pragma unroll
                for (int c = 0; c < 8; ++c) {
                    float s = k1(2) * v[yr][c];
                    s = fmaf(k1(1), v[yr + 1][c], s);
                    s = fmaf(k1(0), v[yr + 2][c], s);
                    s = fmaf(k1(1), v[yr + 3][c], s);
                    s = fmaf(k1(2), v[yr + 4][c], s);
                    cs[yr][c] = s;
                }
            }

            float* op = out + ch * HW + y0 * IMG_W + x0;
            #pragma unroll
            for (int yr = 0; yr < 4; ++yr) {
                float res[4];
                #pragma unroll
                for (int pc = 0; pc < 4; ++pc) {
                    float g = k1n(2) * cs[yr][pc];
                    g = fmaf(k1n(1), cs[yr][pc + 1], g);
                    g = fmaf(k1n(0), cs[yr][pc + 2], g);
                    g = fmaf(k1n(1), cs[yr][pc + 3], g);
                    g = fmaf(k1n(2), cs[yr][pc + 4], g);
                    const int p = yr * 4 + pc;
                    res[pc] = fmaf(0.6f, g, 0.4f * (bs[p] * frcp(ws[p] + 1e-8f)));
                }
                *(float4*)(op + yr * IMG_W) = make_float4(res[0], res[1], res[2], res[3]);
            }
        }
    }
}

extern "C" void kernel_launch(void* const* d_in, const int* in_sizes, int n_in,
                              void* d_out, int out_size, void* d_ws, size_t ws_size,
                              hipStream_t stream) {
    const float* img = (const float*)d_in[0];
    float* out = (float*)d_out;
    aa_kernel<<<GRID_BLOCKS, 256, 0, stream>>>(img, out);
}